// Round 3
// baseline (102.633 us; speedup 1.0000x reference)
//
#include <hip/hip_runtime.h>

// PerturbedTopK: per (b,n) row of d=1024, top-k (k=102) indices of
// x[b] + sigma*noise[b,n], sorted ascending; out[b, rank, idx] += 1/n.
//
// One WAVE processes TWO rows (interleaved for ILP), 16 elements/lane/row.
// Selection by bitwise binary search with __ballot counting (no LDS, no
// __syncthreads). All per-step control is branchless on wave-uniform
// scalars so the two rows' serial chains interleave. Dead keys are zeroed
// in place (key==0 unreachable from finite inputs). Ranks via shfl_up scan.

#define D_DIM 1024
#define K_SEL 102
#define SIGMA 0.05f
#define ROWS_PER_WAVE 2
#define WAVES_PER_BLOCK 4
#define BLOCK (WAVES_PER_BLOCK * 64)
#define SLOTS 16  // D_DIM / 64 elements per lane per row

__device__ __forceinline__ unsigned int float_to_key(float f) {
    unsigned int u = __float_as_uint(f);
    return (u & 0x80000000u) ? ~u : (u | 0x80000000u);  // larger float -> larger uint
}

__device__ __forceinline__ void scatter_row(float* orow, unsigned int run,
                                            unsigned int sel, unsigned int alive,
                                            unsigned int kkf, int base_i, float inv_n) {
    #pragma unroll
    for (int j = 0; j < SLOTS; ++j) {
        const unsigned int gtp = run >> 16;
        const unsigned int eqp = run & 0xFFFFu;
        if (sel & (1u << j)) {
            const unsigned int rank = gtp + (eqp < kkf ? eqp : kkf);
            atomicAdd(orow + (size_t)rank * D_DIM + (base_i + j), inv_n);
            run += 0x10000u;
        } else if (alive & (1u << j)) {
            if (eqp < kkf)
                atomicAdd(orow + (size_t)(gtp + eqp) * D_DIM + (base_i + j), inv_n);
            run += 1u;
        }
    }
}

__global__ __launch_bounds__(BLOCK)
void ptopk_kernel(const float* __restrict__ x,
                  const float* __restrict__ noise,
                  float* __restrict__ out,
                  int n_samples, float inv_n, int nrows) {
    const int wid  = threadIdx.x >> 6;
    const int lane = threadIdx.x & 63;
    const int pair = blockIdx.x * WAVES_PER_BLOCK + wid;
    const int r0   = pair * 2;          // rows r0, r0+1 (nrows even; n_samples=250
    if (r0 >= nrows) return;            //  even, so both rows share one batch b)
    const int bb = r0 / n_samples;

    const float4* xr = reinterpret_cast<const float4*>(x + (size_t)bb * D_DIM + lane * SLOTS);
    const float4* n0 = reinterpret_cast<const float4*>(noise + (size_t)r0 * D_DIM + lane * SLOTS);
    const float4* n1 = reinterpret_cast<const float4*>(noise + (size_t)(r0 + 1) * D_DIM + lane * SLOTS);

    unsigned int k0[SLOTS], k1[SLOTS];
    #pragma unroll
    for (int c = 0; c < 4; ++c) {
        const float4 xv = xr[c];
        const float4 a  = n0[c];
        const float4 b  = n1[c];
        k0[c*4+0] = float_to_key(fmaf(a.x, SIGMA, xv.x));
        k0[c*4+1] = float_to_key(fmaf(a.y, SIGMA, xv.y));
        k0[c*4+2] = float_to_key(fmaf(a.z, SIGMA, xv.z));
        k0[c*4+3] = float_to_key(fmaf(a.w, SIGMA, xv.w));
        k1[c*4+0] = float_to_key(fmaf(b.x, SIGMA, xv.x));
        k1[c*4+1] = float_to_key(fmaf(b.y, SIGMA, xv.y));
        k1[c*4+2] = float_to_key(fmaf(b.z, SIGMA, xv.z));
        k1[c*4+3] = float_to_key(fmaf(b.w, SIGMA, xv.w));
    }

    // ---- bitwise top-k select, two rows interleaved ----
    unsigned int sel0 = 0u, sel1 = 0u;
    unsigned int kk0 = K_SEL, kk1 = K_SEL;
    unsigned int ca0 = D_DIM, ca1 = D_DIM;

    for (int shift = 31; shift >= 0; --shift) {
        const unsigned int m = 1u << shift;
        unsigned int c0 = 0, c1 = 0;
        unsigned int hb0[SLOTS], hb1[SLOTS];
        #pragma unroll
        for (int j = 0; j < SLOTS; ++j) {
            hb0[j] = k0[j] & m;
            hb1[j] = k1[j] & m;
            c0 += (unsigned int)__popcll(__ballot(hb0[j]));
            c1 += (unsigned int)__popcll(__ballot(hb1[j]));
        }
        const bool t0 = (kk0 <= c0);   // wave-uniform
        const bool t1 = (kk1 <= c1);
        #pragma unroll
        for (int j = 0; j < SLOTS; ++j) {
            const bool h0 = hb0[j] != 0u;
            const bool h1 = hb1[j] != 0u;
            sel0 |= (h0 && !t0) ? (1u << j) : 0u;   // bit=0 step: bit-1 keys selected
            sel1 |= (h1 && !t1) ? (1u << j) : 0u;
            k0[j] = (h0 == t0) ? k0[j] : 0u;        // keep iff matches surviving class
            k1[j] = (h1 == t1) ? k1[j] : 0u;
        }
        kk0 = t0 ? kk0 : (kk0 - c0);  ca0 = t0 ? c0 : (ca0 - c0);
        kk1 = t1 ? kk1 : (kk1 - c1);  ca1 = t1 ? c1 : (ca1 - c1);
        if (kk0 == ca0 && kk1 == ca1) break;  // all remaining live keys selected
    }

    unsigned int alive0 = 0u, alive1 = 0u;
    #pragma unroll
    for (int j = 0; j < SLOTS; ++j) {
        alive0 |= k0[j] ? (1u << j) : 0u;
        alive1 |= k1[j] ? (1u << j) : 0u;
    }

    // ---- ranks: exclusive prefix over lanes of packed (gt<<16 | eq), both rows ----
    const unsigned int mine0 = ((unsigned int)__popc(sel0) << 16) | (unsigned int)__popc(alive0);
    const unsigned int mine1 = ((unsigned int)__popc(sel1) << 16) | (unsigned int)__popc(alive1);
    unsigned int inc0 = mine0, inc1 = mine1;
    #pragma unroll
    for (int off = 1; off < 64; off <<= 1) {
        const unsigned int a = __shfl_up(inc0, off, 64);
        const unsigned int b = __shfl_up(inc1, off, 64);
        if (lane >= off) { inc0 += a; inc1 += b; }
    }

    float* orow = out + (size_t)bb * (K_SEL * D_DIM);
    const int base_i = lane * SLOTS;
    scatter_row(orow, inc0 - mine0, sel0, alive0, kk0, base_i, inv_n);
    scatter_row(orow, inc1 - mine1, sel1, alive1, kk1, base_i, inv_n);
}

__global__ __launch_bounds__(256)
void zero_kernel(float4* __restrict__ p, int n4) {
    const int i = blockIdx.x * 256 + threadIdx.x;
    if (i < n4) p[i] = make_float4(0.f, 0.f, 0.f, 0.f);
}

extern "C" void kernel_launch(void* const* d_in, const int* in_sizes, int n_in,
                              void* d_out, int out_size, void* d_ws, size_t ws_size,
                              hipStream_t stream) {
    const float* x     = (const float*)d_in[0];
    const float* noise = (const float*)d_in[1];
    float* out = (float*)d_out;

    const int d = D_DIM;                       // 1024
    const int b = in_sizes[0] / d;             // 32
    const int n = in_sizes[1] / in_sizes[0];   // 250
    const int rows = b * n;                    // 8000

    // harness poisons d_out once and never re-poisons between replays:
    // zero it every call before the atomic scatter (out_size % 4 == 0 here).
    const int n4 = out_size / 4;
    zero_kernel<<<(n4 + 255) / 256, 256, 0, stream>>>((float4*)out, n4);

    const int pairs = rows / 2;
    const int grid = (pairs + WAVES_PER_BLOCK - 1) / WAVES_PER_BLOCK;
    ptopk_kernel<<<grid, BLOCK, 0, stream>>>(x, noise, out, n, 1.0f / (float)n, rows);
}

// Round 4
// 86.130 us; speedup vs baseline: 1.1916x; 1.1916x over previous
//
#include <hip/hip_runtime.h>

// PerturbedTopK: per (b,n) row of d=1024, top-k (k=102) indices of
// x[b] + sigma*noise[b,n], sorted ascending; out[b, rank, idx] += 1/n.
//
// One WAVE (64 lanes) per row, 16 elements/lane. Bitwise binary-search
// select with IMMUTABLE keys: per bit, ballot the predicate
//   (key >> shift) == (prefix>>shift | 1)
// (2 VALU/slot/step). sel/alive classification happens once at the end
// from the resolved prefix. No LDS, no __syncthreads.

#define D_DIM 1024
#define K_SEL 102
#define SIGMA 0.05f
#define WAVES_PER_BLOCK 4
#define BLOCK (WAVES_PER_BLOCK * 64)
#define SLOTS 16  // D_DIM / 64 elements per lane

__device__ __forceinline__ unsigned int float_to_key(float f) {
    unsigned int u = __float_as_uint(f);
    return (u & 0x80000000u) ? ~u : (u | 0x80000000u);  // larger float -> larger uint
}

__global__ __launch_bounds__(BLOCK)
void ptopk_kernel(const float* __restrict__ x,
                  const float* __restrict__ noise,
                  float* __restrict__ out,
                  int n_samples, float inv_n, int nrows) {
    const int wid  = threadIdx.x >> 6;
    const int lane = threadIdx.x & 63;
    const int row  = blockIdx.x * WAVES_PER_BLOCK + wid;
    if (row >= nrows) return;                    // wave-uniform
    const int bb = row / n_samples;

    const float4* nrow =
        reinterpret_cast<const float4*>(noise + (size_t)row * D_DIM + lane * SLOTS);
    const float4* xrow =
        reinterpret_cast<const float4*>(x + (size_t)bb * D_DIM + lane * SLOTS);

    unsigned int key[SLOTS];
    #pragma unroll
    for (int c = 0; c < 4; ++c) {
        const float4 nv = nrow[c];
        const float4 xv = xrow[c];
        key[c*4+0] = float_to_key(fmaf(nv.x, SIGMA, xv.x));
        key[c*4+1] = float_to_key(fmaf(nv.y, SIGMA, xv.y));
        key[c*4+2] = float_to_key(fmaf(nv.z, SIGMA, xv.z));
        key[c*4+3] = float_to_key(fmaf(nv.w, SIGMA, xv.w));
    }

    // ---- bitwise top-k threshold search, keys immutable ----
    // Invariant entering step at 'shift' (bits 31..shift+1 of prefix decided):
    //   selected-so-far = keys with (key>>(shift+1)) > (prefix>>(shift+1)),
    //   alive           = keys with (key>>(shift+1)) == (prefix>>(shift+1)),
    //   ca = |alive|, kk = picks still needed from alive.
    unsigned int kk = K_SEL;
    unsigned int ca = D_DIM;
    unsigned int prefix = 0u;
    int esh = 0;

    for (int shift = 31; shift >= 0; --shift) {
        const unsigned int target = (prefix >> shift) | 1u;  // alive && bit set
        unsigned int c1 = 0;
        #pragma unroll
        for (int j = 0; j < SLOTS; ++j)
            c1 += (unsigned int)__popcll(__ballot((key[j] >> shift) == target));

        if (kk <= c1) { prefix |= (1u << shift); ca = c1; }  // bit resolves to 1
        else          { kk -= c1; ca -= c1; }                // bit-1 keys selected
        if (kk == ca) { esh = shift; break; }  // all remaining alive are selected
    }

    // ---- classify once against resolved prefix at exit shift ----
    const unsigned int P = prefix >> esh;
    unsigned int sel = 0u, alive = 0u;
    #pragma unroll
    for (int j = 0; j < SLOTS; ++j) {
        const unsigned int ks = key[j] >> esh;
        sel   |= (ks > P)  ? (1u << j) : 0u;
        alive |= (ks == P) ? (1u << j) : 0u;
    }
    const unsigned int kkf = kk;  // # of 'alive' to take, ascending index order

    // ---- ranks: exclusive prefix over lanes of packed (gt<<16 | eq) ----
    const unsigned int mine =
        ((unsigned int)__popc(sel) << 16) | (unsigned int)__popc(alive);
    unsigned int incl = mine;
    #pragma unroll
    for (int off = 1; off < 64; off <<= 1) {
        const unsigned int t = __shfl_up(incl, off, 64);
        if (lane >= off) incl += t;
    }
    unsigned int run = incl - mine;  // exclusive prefix (packed)

    float* orow = out + (size_t)bb * (K_SEL * D_DIM);
    const int base_i = lane * SLOTS;
    #pragma unroll
    for (int j = 0; j < SLOTS; ++j) {
        const unsigned int gtp = run >> 16;
        const unsigned int eqp = run & 0xFFFFu;
        if (sel & (1u << j)) {
            const unsigned int rank = gtp + (eqp < kkf ? eqp : kkf);
            atomicAdd(orow + (size_t)rank * D_DIM + (base_i + j), inv_n);
            run += 0x10000u;
        } else if (alive & (1u << j)) {
            if (eqp < kkf)
                atomicAdd(orow + (size_t)(gtp + eqp) * D_DIM + (base_i + j), inv_n);
            run += 1u;
        }
    }
}

extern "C" void kernel_launch(void* const* d_in, const int* in_sizes, int n_in,
                              void* d_out, int out_size, void* d_ws, size_t ws_size,
                              hipStream_t stream) {
    const float* x     = (const float*)d_in[0];
    const float* noise = (const float*)d_in[1];
    float* out = (float*)d_out;

    const int d = D_DIM;                       // 1024
    const int b = in_sizes[0] / d;             // 32
    const int n = in_sizes[1] / in_sizes[0];   // 250
    const int rows = b * n;                    // 8000

    // harness poisons d_out once and never re-poisons between replays:
    // zero it every call before the atomic scatter.
    hipMemsetAsync(d_out, 0, (size_t)out_size * sizeof(float), stream);

    const int grid = (rows + WAVES_PER_BLOCK - 1) / WAVES_PER_BLOCK;
    ptopk_kernel<<<grid, BLOCK, 0, stream>>>(x, noise, out, n, 1.0f / (float)n, rows);
}

// Round 5
// 33.692 us; speedup vs baseline: 3.0462x; 2.5564x over previous
//
#include <hip/hip_runtime.h>

// PerturbedTopK: per (b,n) row of d=1024, top-k (k=102) indices of
// x[b] + sigma*noise[b,n], sorted ascending; out[b, rank, idx] += 1/n.
//
// R5: two-phase, zero global atomics (R4's 816K memory-side atomic RMWs
// = 25.5MB HBM write traffic were the bottleneck).
//   Phase A: one wave per row; bitwise ballot binary-search select
//            (R4 logic); store selected u16 index at ws[b][rank][sample].
//   Phase B: one block per (b,rank); LDS histogram of 250 indices;
//            coalesced float4 write of out[b,rank,:]. Writes every cell,
//            so no zeroing pass is needed.

#define D_DIM 1024
#define K_SEL 102
#define SIGMA 0.05f
#define WAVES_PER_BLOCK 4
#define BLOCK (WAVES_PER_BLOCK * 64)
#define SLOTS 16  // D_DIM / 64 elements per lane

__device__ __forceinline__ unsigned int float_to_key(float f) {
    unsigned int u = __float_as_uint(f);
    return (u & 0x80000000u) ? ~u : (u | 0x80000000u);  // larger float -> larger uint
}

// ---------------- Phase A: select + index store ----------------
template <bool USE_WS>
__global__ __launch_bounds__(BLOCK)
void ptopk_select(const float* __restrict__ x,
                  const float* __restrict__ noise,
                  unsigned short* __restrict__ ws_idx,  // [b][K_SEL][n_samples]
                  float* __restrict__ out,              // fallback path only
                  int n_samples, float inv_n, int nrows) {
    const int wid  = threadIdx.x >> 6;
    const int lane = threadIdx.x & 63;
    const int row  = blockIdx.x * WAVES_PER_BLOCK + wid;
    if (row >= nrows) return;                    // wave-uniform
    const int bb = row / n_samples;
    const int ss = row - bb * n_samples;

    const float4* nrow =
        reinterpret_cast<const float4*>(noise + (size_t)row * D_DIM + lane * SLOTS);
    const float4* xrow =
        reinterpret_cast<const float4*>(x + (size_t)bb * D_DIM + lane * SLOTS);

    unsigned int key[SLOTS];
    #pragma unroll
    for (int c = 0; c < 4; ++c) {
        const float4 nv = nrow[c];
        const float4 xv = xrow[c];
        key[c*4+0] = float_to_key(fmaf(nv.x, SIGMA, xv.x));
        key[c*4+1] = float_to_key(fmaf(nv.y, SIGMA, xv.y));
        key[c*4+2] = float_to_key(fmaf(nv.z, SIGMA, xv.z));
        key[c*4+3] = float_to_key(fmaf(nv.w, SIGMA, xv.w));
    }

    // ---- bitwise top-k threshold search, keys immutable ----
    unsigned int kk = K_SEL;
    unsigned int ca = D_DIM;
    unsigned int prefix = 0u;
    int esh = 0;

    for (int shift = 31; shift >= 0; --shift) {
        const unsigned int target = (prefix >> shift) | 1u;  // alive && bit set
        unsigned int c1 = 0;
        #pragma unroll
        for (int j = 0; j < SLOTS; ++j)
            c1 += (unsigned int)__popcll(__ballot((key[j] >> shift) == target));

        if (kk <= c1) { prefix |= (1u << shift); ca = c1; }  // bit resolves to 1
        else          { kk -= c1; ca -= c1; }                // bit-1 keys selected
        if (kk == ca) { esh = shift; break; }  // all remaining alive are selected
    }

    // ---- classify once against resolved prefix ----
    const unsigned int P = prefix >> esh;
    unsigned int sel = 0u, alive = 0u;
    #pragma unroll
    for (int j = 0; j < SLOTS; ++j) {
        const unsigned int ks = key[j] >> esh;
        sel   |= (ks > P)  ? (1u << j) : 0u;
        alive |= (ks == P) ? (1u << j) : 0u;
    }
    const unsigned int kkf = kk;  // # of ties to take, ascending index order

    // ---- ranks: exclusive prefix over lanes of packed (gt<<16 | eq) ----
    const unsigned int mine =
        ((unsigned int)__popc(sel) << 16) | (unsigned int)__popc(alive);
    unsigned int incl = mine;
    #pragma unroll
    for (int off = 1; off < 64; off <<= 1) {
        const unsigned int t = __shfl_up(incl, off, 64);
        if (lane >= off) incl += t;
    }
    unsigned int run = incl - mine;  // exclusive prefix (packed)

    // rank slot for sample ss of batch bb, rank r lives at wb[r * n_samples]
    unsigned short* wb = ws_idx + (size_t)bb * K_SEL * n_samples + ss;
    float* orow = out + (size_t)bb * (K_SEL * D_DIM);
    const int base_i = lane * SLOTS;
    #pragma unroll
    for (int j = 0; j < SLOTS; ++j) {
        const unsigned int gtp = run >> 16;
        const unsigned int eqp = run & 0xFFFFu;
        if (sel & (1u << j)) {
            const unsigned int rank = gtp + (eqp < kkf ? eqp : kkf);
            if (USE_WS) wb[(size_t)rank * n_samples] = (unsigned short)(base_i + j);
            else atomicAdd(orow + (size_t)rank * D_DIM + (base_i + j), inv_n);
            run += 0x10000u;
        } else if (alive & (1u << j)) {
            if (eqp < kkf) {
                if (USE_WS) wb[(size_t)(gtp + eqp) * n_samples] = (unsigned short)(base_i + j);
                else atomicAdd(orow + (size_t)(gtp + eqp) * D_DIM + (base_i + j), inv_n);
            }
            run += 1u;
        }
    }
}

// ---------------- Phase B: histogram + coalesced write ----------------
__global__ __launch_bounds__(256)
void ptopk_hist(const unsigned short* __restrict__ ws_idx,  // [b*K_SEL][n_samples]
                float* __restrict__ out,                    // [b*K_SEL][D_DIM]
                int n_samples, float inv_n) {
    __shared__ unsigned int cnt[D_DIM];
    const int tid = threadIdx.x;
    #pragma unroll
    for (int c = 0; c < D_DIM / 256; ++c) cnt[c * 256 + tid] = 0u;
    __syncthreads();

    const unsigned short* src = ws_idx + (size_t)blockIdx.x * n_samples;
    for (int s = tid; s < n_samples; s += 256)
        atomicAdd(&cnt[src[s]], 1u);
    __syncthreads();

    float4* dst = reinterpret_cast<float4*>(out + (size_t)blockIdx.x * D_DIM);
    const int i = tid * 4;
    dst[tid] = make_float4(cnt[i] * inv_n, cnt[i + 1] * inv_n,
                           cnt[i + 2] * inv_n, cnt[i + 3] * inv_n);
}

__global__ __launch_bounds__(256)
void zero_kernel(float4* __restrict__ p, int n4) {
    const int i = blockIdx.x * 256 + threadIdx.x;
    if (i < n4) p[i] = make_float4(0.f, 0.f, 0.f, 0.f);
}

extern "C" void kernel_launch(void* const* d_in, const int* in_sizes, int n_in,
                              void* d_out, int out_size, void* d_ws, size_t ws_size,
                              hipStream_t stream) {
    const float* x     = (const float*)d_in[0];
    const float* noise = (const float*)d_in[1];
    float* out = (float*)d_out;

    const int d = D_DIM;                       // 1024
    const int b = in_sizes[0] / d;             // 32
    const int n = in_sizes[1] / in_sizes[0];   // 250
    const int rows = b * n;                    // 8000
    const float inv_n = 1.0f / (float)n;
    const int grid = (rows + WAVES_PER_BLOCK - 1) / WAVES_PER_BLOCK;

    const size_t ws_needed = (size_t)b * K_SEL * n * sizeof(unsigned short);
    if (ws_size >= ws_needed) {
        // two-phase, atomic-free path
        unsigned short* ws_idx = (unsigned short*)d_ws;
        ptopk_select<true><<<grid, BLOCK, 0, stream>>>(x, noise, ws_idx, out,
                                                       n, inv_n, rows);
        ptopk_hist<<<b * K_SEL, 256, 0, stream>>>(ws_idx, out, n, inv_n);
    } else {
        // fallback: R4 atomic-scatter path
        const int n4 = out_size / 4;
        zero_kernel<<<(n4 + 255) / 256, 256, 0, stream>>>((float4*)out, n4);
        ptopk_select<false><<<grid, BLOCK, 0, stream>>>(x, noise, nullptr, out,
                                                        n, inv_n, rows);
    }
}

// Round 6
// 33.173 us; speedup vs baseline: 3.0939x; 1.0156x over previous
//
#include <hip/hip_runtime.h>

// PerturbedTopK: per (b,n) row of d=1024, top-k (k=102) indices of
// x[b] + sigma*noise[b,n], sorted ascending; out[b, rank, idx] += 1/n.
//
// R6: two-phase (R5), with
//  - radix-4 select using GE-ballots on the immutable full key:
//      #{key >= prefix | d<<shift} = nsel + #{alive, digit >= d}
//    so digit choice is "largest d with g_d >= K_SEL"; exit when g_d == K_SEL.
//    ~11 serial steps instead of ~22.
//  - ws layout [b][sample][rank]: phase-A's 102 u16 stores per wave are
//    rank-ascending == index-ascending -> one contiguous 204B run.
//    Phase B reads strided (stride K_SEL*2B) but L2-hot.

#define D_DIM 1024
#define K_SEL 102
#define SIGMA 0.05f
#define WAVES_PER_BLOCK 4
#define BLOCK (WAVES_PER_BLOCK * 64)
#define SLOTS 16  // D_DIM / 64 elements per lane

__device__ __forceinline__ unsigned int float_to_key(float f) {
    unsigned int u = __float_as_uint(f);
    return (u & 0x80000000u) ? ~u : (u | 0x80000000u);  // larger float -> larger uint
}

// ---------------- Phase A: select + index store ----------------
template <bool USE_WS>
__global__ __launch_bounds__(BLOCK)
void ptopk_select(const float* __restrict__ x,
                  const float* __restrict__ noise,
                  unsigned short* __restrict__ ws_idx,  // [b][n_samples][K_SEL]
                  float* __restrict__ out,              // fallback path only
                  int n_samples, float inv_n, int nrows) {
    const int wid  = threadIdx.x >> 6;
    const int lane = threadIdx.x & 63;
    const int row  = blockIdx.x * WAVES_PER_BLOCK + wid;
    if (row >= nrows) return;                    // wave-uniform
    const int bb = row / n_samples;
    const int ss = row - bb * n_samples;

    const float4* nrow =
        reinterpret_cast<const float4*>(noise + (size_t)row * D_DIM + lane * SLOTS);
    const float4* xrow =
        reinterpret_cast<const float4*>(x + (size_t)bb * D_DIM + lane * SLOTS);

    unsigned int key[SLOTS];
    #pragma unroll
    for (int c = 0; c < 4; ++c) {
        const float4 nv = nrow[c];
        const float4 xv = xrow[c];
        key[c*4+0] = float_to_key(fmaf(nv.x, SIGMA, xv.x));
        key[c*4+1] = float_to_key(fmaf(nv.y, SIGMA, xv.y));
        key[c*4+2] = float_to_key(fmaf(nv.z, SIGMA, xv.z));
        key[c*4+3] = float_to_key(fmaf(nv.w, SIGMA, xv.w));
    }

    // ---- radix-4 top-k threshold search, GE-ballots on full keys ----
    // Invariant: selected = {key >= prefix + (4<<shift)} (count nsel),
    //            alive    = {prefix <= key < prefix + (4<<shift)} (count ca),
    //            picks remaining from alive = K_SEL - nsel.
    unsigned int prefix = 0u, nsel = 0u, ca = D_DIM;
    int esh = 0;

    for (int shift = 30; shift >= 0; shift -= 2) {
        const unsigned int b1 = prefix | (1u << shift);
        const unsigned int b2 = prefix | (2u << shift);
        const unsigned int b3 = prefix | (3u << shift);
        unsigned int g1 = 0, g2 = 0, g3 = 0;
        #pragma unroll
        for (int j = 0; j < SLOTS; ++j) {
            g1 += (unsigned int)__popcll(__ballot(key[j] >= b1));
            g2 += (unsigned int)__popcll(__ballot(key[j] >= b2));
            g3 += (unsigned int)__popcll(__ballot(key[j] >= b3));
        }
        const unsigned int g0 = nsel + ca;   // == #{key >= prefix}
        unsigned int gd;
        if (g3 >= K_SEL)      { prefix = b3; ca = g3 - nsel; gd = g3; }
        else if (g2 >= K_SEL) { prefix = b2; ca = g2 - g3; nsel = g3; gd = g2; }
        else if (g1 >= K_SEL) { prefix = b1; ca = g1 - g2; nsel = g2; gd = g1; }
        else                  {              ca = g0 - g1; nsel = g1; gd = g0; }
        if (gd == K_SEL) { esh = shift; break; }  // all remaining alive selected
    }

    // ---- classify once against resolved prefix ----
    const unsigned int P = prefix >> esh;
    unsigned int sel = 0u, alive = 0u;
    #pragma unroll
    for (int j = 0; j < SLOTS; ++j) {
        const unsigned int ks = key[j] >> esh;
        sel   |= (ks > P)  ? (1u << j) : 0u;
        alive |= (ks == P) ? (1u << j) : 0u;
    }
    const unsigned int kkf = K_SEL - nsel;  // # of ties to take, ascending index

    // ---- ranks: exclusive prefix over lanes of packed (gt<<16 | eq) ----
    const unsigned int mine =
        ((unsigned int)__popc(sel) << 16) | (unsigned int)__popc(alive);
    unsigned int incl = mine;
    #pragma unroll
    for (int off = 1; off < 64; off <<= 1) {
        const unsigned int t = __shfl_up(incl, off, 64);
        if (lane >= off) incl += t;
    }
    unsigned int run = incl - mine;  // exclusive prefix (packed)

    // ws slot for (bb, ss): contiguous K_SEL u16 ranks -> coalesced stores
    unsigned short* wb = ws_idx + ((size_t)bb * n_samples + ss) * K_SEL;
    float* orow = out + (size_t)bb * (K_SEL * D_DIM);
    const int base_i = lane * SLOTS;
    #pragma unroll
    for (int j = 0; j < SLOTS; ++j) {
        const unsigned int gtp = run >> 16;
        const unsigned int eqp = run & 0xFFFFu;
        if (sel & (1u << j)) {
            const unsigned int rank = gtp + (eqp < kkf ? eqp : kkf);
            if (USE_WS) wb[rank] = (unsigned short)(base_i + j);
            else atomicAdd(orow + (size_t)rank * D_DIM + (base_i + j), inv_n);
            run += 0x10000u;
        } else if (alive & (1u << j)) {
            if (eqp < kkf) {
                if (USE_WS) wb[gtp + eqp] = (unsigned short)(base_i + j);
                else atomicAdd(orow + (size_t)(gtp + eqp) * D_DIM + (base_i + j), inv_n);
            }
            run += 1u;
        }
    }
}

// ---------------- Phase B: histogram + coalesced write ----------------
__global__ __launch_bounds__(256)
void ptopk_hist(const unsigned short* __restrict__ ws_idx,  // [b][n_samples][K_SEL]
                float* __restrict__ out,                    // [b*K_SEL][D_DIM]
                int n_samples, float inv_n) {
    __shared__ unsigned int cnt[D_DIM];
    const int tid = threadIdx.x;
    #pragma unroll
    for (int c = 0; c < D_DIM / 256; ++c) cnt[c * 256 + tid] = 0u;
    __syncthreads();

    const int b_ = blockIdx.x / K_SEL;
    const int r_ = blockIdx.x - b_ * K_SEL;
    const unsigned short* src = ws_idx + (size_t)b_ * n_samples * K_SEL + r_;
    for (int s = tid; s < n_samples; s += 256)
        atomicAdd(&cnt[src[(size_t)s * K_SEL]], 1u);
    __syncthreads();

    float4* dst = reinterpret_cast<float4*>(out + (size_t)blockIdx.x * D_DIM);
    const int i = tid * 4;
    dst[tid] = make_float4(cnt[i] * inv_n, cnt[i + 1] * inv_n,
                           cnt[i + 2] * inv_n, cnt[i + 3] * inv_n);
}

__global__ __launch_bounds__(256)
void zero_kernel(float4* __restrict__ p, int n4) {
    const int i = blockIdx.x * 256 + threadIdx.x;
    if (i < n4) p[i] = make_float4(0.f, 0.f, 0.f, 0.f);
}

extern "C" void kernel_launch(void* const* d_in, const int* in_sizes, int n_in,
                              void* d_out, int out_size, void* d_ws, size_t ws_size,
                              hipStream_t stream) {
    const float* x     = (const float*)d_in[0];
    const float* noise = (const float*)d_in[1];
    float* out = (float*)d_out;

    const int d = D_DIM;                       // 1024
    const int b = in_sizes[0] / d;             // 32
    const int n = in_sizes[1] / in_sizes[0];   // 250
    const int rows = b * n;                    // 8000
    const float inv_n = 1.0f / (float)n;
    const int grid = (rows + WAVES_PER_BLOCK - 1) / WAVES_PER_BLOCK;

    const size_t ws_needed = (size_t)b * K_SEL * n * sizeof(unsigned short);
    if (ws_size >= ws_needed) {
        // two-phase, atomic-free path
        unsigned short* ws_idx = (unsigned short*)d_ws;
        ptopk_select<true><<<grid, BLOCK, 0, stream>>>(x, noise, ws_idx, out,
                                                       n, inv_n, rows);
        ptopk_hist<<<b * K_SEL, 256, 0, stream>>>(ws_idx, out, n, inv_n);
    } else {
        // fallback: atomic-scatter path
        const int n4 = out_size / 4;
        zero_kernel<<<(n4 + 255) / 256, 256, 0, stream>>>((float4*)out, n4);
        ptopk_select<false><<<grid, BLOCK, 0, stream>>>(x, noise, nullptr, out,
                                                        n, inv_n, rows);
    }
}

// Round 7
// 27.965 us; speedup vs baseline: 3.6701x; 1.1863x over previous
//
#include <hip/hip_runtime.h>

// PerturbedTopK: per (b,n) row of d=1024, top-k (k=102) indices of
// x[b] + sigma*noise[b,n], sorted ascending; out[b, rank, idx] += 1/n.
//
// R7: two-phase (R5/R6), select rewritten to avoid the shared SALU:
//  - counts = per-lane VALU compares (4 indep accumulators) + DPP-tree
//    wave reduce + one readlane (6 SALU/step instead of ~60 s_bcnt/adds).
//  - interpolation search on the uint key line with statistical initial
//    bracket (keys of 1.04/1.52 ~ N(0,1) 90th pctile), bisection
//    safeguard every other step; exact exit on c_lo==K or width-1.

#define D_DIM 1024
#define K_SEL 102
#define SIGMA 0.05f
#define WAVES_PER_BLOCK 4
#define BLOCK (WAVES_PER_BLOCK * 64)
#define SLOTS 16  // D_DIM / 64 elements per lane

__device__ __forceinline__ unsigned int float_to_key(float f) {
    unsigned int u = __float_as_uint(f);
    return (u & 0x80000000u) ? ~u : (u | 0x80000000u);  // larger float -> larger uint
}

// wave64 sum via DPP row_shr tree + row broadcasts; total lands in lane 63.
__device__ __forceinline__ unsigned int wave_sum_u32(unsigned int v) {
    v += (unsigned int)__builtin_amdgcn_update_dpp(0, (int)v, 0x111, 0xF, 0xF, false); // row_shr:1
    v += (unsigned int)__builtin_amdgcn_update_dpp(0, (int)v, 0x112, 0xF, 0xF, false); // row_shr:2
    v += (unsigned int)__builtin_amdgcn_update_dpp(0, (int)v, 0x114, 0xF, 0xF, false); // row_shr:4
    v += (unsigned int)__builtin_amdgcn_update_dpp(0, (int)v, 0x118, 0xF, 0xF, false); // row_shr:8
    v += (unsigned int)__builtin_amdgcn_update_dpp(0, (int)v, 0x142, 0xA, 0xF, false); // row_bcast:15
    v += (unsigned int)__builtin_amdgcn_update_dpp(0, (int)v, 0x143, 0xC, 0xF, false); // row_bcast:31
    return (unsigned int)__builtin_amdgcn_readlane((int)v, 63);
}

// #{key >= m} across the wave's 1024 elements; pure VALU + 1 readlane.
__device__ __forceinline__ unsigned int count_ge(const unsigned int* key, unsigned int m) {
    unsigned int a = 0, b = 0, c = 0, d = 0;   // 4 chains: no carry serialization
    #pragma unroll
    for (int j = 0; j < SLOTS; j += 4) {
        a += (key[j + 0] >= m) ? 1u : 0u;
        b += (key[j + 1] >= m) ? 1u : 0u;
        c += (key[j + 2] >= m) ? 1u : 0u;
        d += (key[j + 3] >= m) ? 1u : 0u;
    }
    return wave_sum_u32((a + b) + (c + d));
}

// ---------------- Phase A: select + index store ----------------
template <bool USE_WS>
__global__ __launch_bounds__(BLOCK)
void ptopk_select(const float* __restrict__ x,
                  const float* __restrict__ noise,
                  unsigned short* __restrict__ ws_idx,  // [b][n_samples][K_SEL]
                  float* __restrict__ out,              // fallback path only
                  int n_samples, float inv_n, int nrows) {
    const int wid  = threadIdx.x >> 6;
    const int lane = threadIdx.x & 63;
    const int row  = blockIdx.x * WAVES_PER_BLOCK + wid;
    if (row >= nrows) return;                    // wave-uniform
    const int bb = row / n_samples;
    const int ss = row - bb * n_samples;

    const float4* nrow =
        reinterpret_cast<const float4*>(noise + (size_t)row * D_DIM + lane * SLOTS);
    const float4* xrow =
        reinterpret_cast<const float4*>(x + (size_t)bb * D_DIM + lane * SLOTS);

    unsigned int key[SLOTS];
    #pragma unroll
    for (int c = 0; c < 4; ++c) {
        const float4 nv = nrow[c];
        const float4 xv = xrow[c];
        key[c*4+0] = float_to_key(fmaf(nv.x, SIGMA, xv.x));
        key[c*4+1] = float_to_key(fmaf(nv.y, SIGMA, xv.y));
        key[c*4+2] = float_to_key(fmaf(nv.z, SIGMA, xv.z));
        key[c*4+3] = float_to_key(fmaf(nv.w, SIGMA, xv.w));
    }

    // ---- initial statistical bracket: one pass, both counts packed ----
    // For N(0,1)-ish rows the k=102/1024 threshold lies in [1.04, 1.52)
    // essentially always; the generic bracket logic below is exact anyway.
    const unsigned int KLO = float_to_key(1.04f);
    const unsigned int KHI = float_to_key(1.52f);
    {
    }
    unsigned int p0 = 0, p1 = 0;
    #pragma unroll
    for (int j = 0; j < SLOTS; j += 2) {
        p0 += ((key[j]   >= KLO) ? 1u : 0u) + ((key[j]   >= KHI) ? 0x10000u : 0u);
        p1 += ((key[j+1] >= KLO) ? 1u : 0u) + ((key[j+1] >= KHI) ? 0x10000u : 0u);
    }
    const unsigned int packed = wave_sum_u32(p0 + p1);
    const unsigned int cKLO = packed & 0xFFFFu;
    const unsigned int cKHI = packed >> 16;

    unsigned int lo, hi, c_lo, c_hi;
    if (cKLO < K_SEL)        { lo = 0u;  c_lo = D_DIM; hi = KLO;         c_hi = cKLO; }
    else if (cKHI >= K_SEL)  { lo = KHI; c_lo = cKHI;  hi = 0xFFFFFFFFu; c_hi = 0u;   }
    else                     { lo = KLO; c_lo = cKLO;  hi = KHI;         c_hi = cKHI; }
    // Note: no key can be 0 (requires -NaN input) or 0xFFFFFFFF (+NaN), so
    // c(0)=D_DIM and c(0xFFFFFFFF)=0 hold without counting.

    // ---- bracket search: interpolation + bisection safeguard ----
    // Invariant: c_lo = #{key>=lo} >= K_SEL > c_hi = #{key>=hi}; strict
    // shrink each iter -> terminates; typically ~4-6 probes.
    int it = 0;
    while (c_lo != K_SEL && (hi - lo) > 1u) {
        const unsigned int span = hi - lo;
        unsigned int off;
        if (it & 1) {
            off = span >> 1;
        } else {
            const float frac = (float)(c_lo - K_SEL) / (float)(c_lo - c_hi);
            off = (unsigned int)(frac * (float)span);
        }
        if (off < 1u) off = 1u;
        if (off > span - 1u) off = span - 1u;
        const unsigned int m = lo + off;
        const unsigned int cm = count_ge(key, m);
        if (cm >= K_SEL) { lo = m; c_lo = cm; }
        else             { hi = m; c_hi = cm; }
        ++it;
    }

    // ---- end state ----
    unsigned int SEL_B, kkf, tieK;
    if (c_lo == K_SEL) { SEL_B = lo; kkf = 0u;            tieK = 0u; } // no ties; key==0 impossible
    else               { SEL_B = hi; kkf = K_SEL - c_hi;  tieK = lo; } // hi == lo+1, T == lo

    unsigned int sel = 0u, alive = 0u;
    #pragma unroll
    for (int j = 0; j < SLOTS; ++j) {
        sel   |= (key[j] >= SEL_B) ? (1u << j) : 0u;
        alive |= (key[j] == tieK)  ? (1u << j) : 0u;
    }

    // ---- ranks: exclusive prefix over lanes of packed (gt<<16 | eq) ----
    const unsigned int mine =
        ((unsigned int)__popc(sel) << 16) | (unsigned int)__popc(alive);
    unsigned int incl = mine;
    #pragma unroll
    for (int off = 1; off < 64; off <<= 1) {
        const unsigned int t = __shfl_up(incl, off, 64);
        if (lane >= off) incl += t;
    }
    unsigned int run = incl - mine;  // exclusive prefix (packed)

    unsigned short* wb = ws_idx + ((size_t)bb * n_samples + ss) * K_SEL;
    float* orow = out + (size_t)bb * (K_SEL * D_DIM);
    const int base_i = lane * SLOTS;
    #pragma unroll
    for (int j = 0; j < SLOTS; ++j) {
        const unsigned int gtp = run >> 16;
        const unsigned int eqp = run & 0xFFFFu;
        if (sel & (1u << j)) {
            const unsigned int rank = gtp + (eqp < kkf ? eqp : kkf);
            if (USE_WS) wb[rank] = (unsigned short)(base_i + j);
            else atomicAdd(orow + (size_t)rank * D_DIM + (base_i + j), inv_n);
            run += 0x10000u;
        } else if (alive & (1u << j)) {
            if (eqp < kkf) {
                if (USE_WS) wb[gtp + eqp] = (unsigned short)(base_i + j);
                else atomicAdd(orow + (size_t)(gtp + eqp) * D_DIM + (base_i + j), inv_n);
            }
            run += 1u;
        }
    }
}

// ---------------- Phase B: histogram + coalesced write ----------------
__global__ __launch_bounds__(256)
void ptopk_hist(const unsigned short* __restrict__ ws_idx,  // [b][n_samples][K_SEL]
                float* __restrict__ out,                    // [b*K_SEL][D_DIM]
                int n_samples, float inv_n) {
    __shared__ unsigned int cnt[D_DIM];
    const int tid = threadIdx.x;
    #pragma unroll
    for (int c = 0; c < D_DIM / 256; ++c) cnt[c * 256 + tid] = 0u;
    __syncthreads();

    const int b_ = blockIdx.x / K_SEL;
    const int r_ = blockIdx.x - b_ * K_SEL;
    const unsigned short* src = ws_idx + (size_t)b_ * n_samples * K_SEL + r_;
    for (int s = tid; s < n_samples; s += 256)
        atomicAdd(&cnt[src[(size_t)s * K_SEL]], 1u);
    __syncthreads();

    float4* dst = reinterpret_cast<float4*>(out + (size_t)blockIdx.x * D_DIM);
    const int i = tid * 4;
    dst[tid] = make_float4(cnt[i] * inv_n, cnt[i + 1] * inv_n,
                           cnt[i + 2] * inv_n, cnt[i + 3] * inv_n);
}

__global__ __launch_bounds__(256)
void zero_kernel(float4* __restrict__ p, int n4) {
    const int i = blockIdx.x * 256 + threadIdx.x;
    if (i < n4) p[i] = make_float4(0.f, 0.f, 0.f, 0.f);
}

extern "C" void kernel_launch(void* const* d_in, const int* in_sizes, int n_in,
                              void* d_out, int out_size, void* d_ws, size_t ws_size,
                              hipStream_t stream) {
    const float* x     = (const float*)d_in[0];
    const float* noise = (const float*)d_in[1];
    float* out = (float*)d_out;

    const int d = D_DIM;                       // 1024
    const int b = in_sizes[0] / d;             // 32
    const int n = in_sizes[1] / in_sizes[0];   // 250
    const int rows = b * n;                    // 8000
    const float inv_n = 1.0f / (float)n;
    const int grid = (rows + WAVES_PER_BLOCK - 1) / WAVES_PER_BLOCK;

    const size_t ws_needed = (size_t)b * K_SEL * n * sizeof(unsigned short);
    if (ws_size >= ws_needed) {
        // two-phase, atomic-free path
        unsigned short* ws_idx = (unsigned short*)d_ws;
        ptopk_select<true><<<grid, BLOCK, 0, stream>>>(x, noise, ws_idx, out,
                                                       n, inv_n, rows);
        ptopk_hist<<<b * K_SEL, 256, 0, stream>>>(ws_idx, out, n, inv_n);
    } else {
        // fallback: atomic-scatter path
        const int n4 = out_size / 4;
        zero_kernel<<<(n4 + 255) / 256, 256, 0, stream>>>((float4*)out, n4);
        ptopk_select<false><<<grid, BLOCK, 0, stream>>>(x, noise, nullptr, out,
                                                        n, inv_n, rows);
    }
}

// Round 8
// 26.876 us; speedup vs baseline: 3.8187x; 1.0405x over previous
//
#include <hip/hip_runtime.h>

// PerturbedTopK: per (b,n) row of d=1024, top-k (k=102) indices of
// x[b] + sigma*noise[b,n], sorted ascending; out[b, rank, idx] += 1/n.
//
// R8: two-phase (R5+), select refined:
//  - 4-bound packed initial grid {1.10,1.22,1.31,1.44} (one pass, 2 DPP trees)
//  - 2 bounds per search pass (interpolated + midpoint, packed 16-bit fields,
//    one DPP tree + one readlane per pass) -> ~4 serial round trips
//  - DPP inclusive scan for ranks (no ds_bpermute), ctz bit-loop scatter
// Exactness: generic bracket invariant c(lo)>=K>c(hi); exits on c(lo)==K
// (unique top-K set) or width-1 (T=lo, first K-c(hi) ties by index).

#define D_DIM 1024
#define K_SEL 102
#define SIGMA 0.05f
#define WAVES_PER_BLOCK 4
#define BLOCK (WAVES_PER_BLOCK * 64)
#define SLOTS 16  // D_DIM / 64 elements per lane

__device__ __forceinline__ unsigned int float_to_key(float f) {
    unsigned int u = __float_as_uint(f);
    return (u & 0x80000000u) ? ~u : (u | 0x80000000u);  // larger float -> larger uint
}

// wave64 inclusive scan (DPP row_shr tree + masked row broadcasts).
__device__ __forceinline__ unsigned int wave_incl_scan(unsigned int v) {
    v += (unsigned int)__builtin_amdgcn_update_dpp(0, (int)v, 0x111, 0xF, 0xF, false); // row_shr:1
    v += (unsigned int)__builtin_amdgcn_update_dpp(0, (int)v, 0x112, 0xF, 0xF, false); // row_shr:2
    v += (unsigned int)__builtin_amdgcn_update_dpp(0, (int)v, 0x114, 0xF, 0xF, false); // row_shr:4
    v += (unsigned int)__builtin_amdgcn_update_dpp(0, (int)v, 0x118, 0xF, 0xF, false); // row_shr:8
    v += (unsigned int)__builtin_amdgcn_update_dpp(0, (int)v, 0x142, 0xA, 0xF, false); // row_bcast:15
    v += (unsigned int)__builtin_amdgcn_update_dpp(0, (int)v, 0x143, 0xC, 0xF, false); // row_bcast:31
    return v;
}
__device__ __forceinline__ unsigned int wave_sum_u32(unsigned int v) {
    return (unsigned int)__builtin_amdgcn_readlane((int)wave_incl_scan(v), 63);
}

// packed counts of {key >= m1} and {key >= m2}<<16 across the wave's 1024 elems
__device__ __forceinline__ unsigned int count_ge2(const unsigned int* key,
                                                  unsigned int m1, unsigned int m2) {
    unsigned int a = 0, b = 0;
    #pragma unroll
    for (int j = 0; j < SLOTS; ++j) {
        a += (key[j] >= m1) ? 1u : 0u;
        b += (key[j] >= m2) ? 1u : 0u;
    }
    return wave_sum_u32(a | (b << 16));
}

// ---------------- Phase A: select + index store ----------------
template <bool USE_WS>
__global__ __launch_bounds__(BLOCK)
void ptopk_select(const float* __restrict__ x,
                  const float* __restrict__ noise,
                  unsigned short* __restrict__ ws_idx,  // [b][n_samples][K_SEL]
                  float* __restrict__ out,              // fallback path only
                  int n_samples, float inv_n, int nrows) {
    const int wid  = threadIdx.x >> 6;
    const int lane = threadIdx.x & 63;
    const int row  = blockIdx.x * WAVES_PER_BLOCK + wid;
    if (row >= nrows) return;                    // wave-uniform
    const int bb = row / n_samples;
    const int ss = row - bb * n_samples;

    const float4* nrow =
        reinterpret_cast<const float4*>(noise + (size_t)row * D_DIM + lane * SLOTS);
    const float4* xrow =
        reinterpret_cast<const float4*>(x + (size_t)bb * D_DIM + lane * SLOTS);

    unsigned int key[SLOTS];
    #pragma unroll
    for (int c = 0; c < 4; ++c) {
        const float4 nv = nrow[c];
        const float4 xv = xrow[c];
        key[c*4+0] = float_to_key(fmaf(nv.x, SIGMA, xv.x));
        key[c*4+1] = float_to_key(fmaf(nv.y, SIGMA, xv.y));
        key[c*4+2] = float_to_key(fmaf(nv.z, SIGMA, xv.z));
        key[c*4+3] = float_to_key(fmaf(nv.w, SIGMA, xv.w));
    }

    // ---- initial 4-bound grid (one pass, two packed DPP reductions) ----
    // threshold order-stat ~ N(1.284, 0.053); grid covers +-3.5 sigma.
    // Outlier rows fall into the generic outer brackets (exact, just slower).
    const unsigned int B1 = float_to_key(1.10f);
    const unsigned int B2 = float_to_key(1.22f);
    const unsigned int B3 = float_to_key(1.31f);
    const unsigned int B4 = float_to_key(1.44f);
    unsigned int pA = 0, pB = 0;
    #pragma unroll
    for (int j = 0; j < SLOTS; ++j) {
        pA += ((key[j] >= B1) ? 1u : 0u) + ((key[j] >= B2) ? 0x10000u : 0u);
        pB += ((key[j] >= B3) ? 1u : 0u) + ((key[j] >= B4) ? 0x10000u : 0u);
    }
    const unsigned int sA = wave_incl_scan(pA);
    const unsigned int sB = wave_incl_scan(pB);
    const unsigned int tA = (unsigned int)__builtin_amdgcn_readlane((int)sA, 63);
    const unsigned int tB = (unsigned int)__builtin_amdgcn_readlane((int)sB, 63);
    const unsigned int c1 = tA & 0xFFFFu, c2 = tA >> 16;
    const unsigned int c3 = tB & 0xFFFFu, c4 = tB >> 16;

    unsigned int lo, hi, c_lo, c_hi;
    if (c4 >= K_SEL)      { lo = B4; c_lo = c4;    hi = 0xFFFFFFFFu; c_hi = 0u; }
    else if (c3 >= K_SEL) { lo = B3; c_lo = c3;    hi = B4; c_hi = c4; }
    else if (c2 >= K_SEL) { lo = B2; c_lo = c2;    hi = B3; c_hi = c3; }
    else if (c1 >= K_SEL) { lo = B1; c_lo = c1;    hi = B2; c_hi = c2; }
    else                  { lo = 0u; c_lo = D_DIM; hi = B1; c_hi = c1; }
    // key==0 (-NaN) and key==0xFFFFFFFF (+NaN) are unreachable from finite
    // inputs, so c(0)=D_DIM and c(MAX)=0 hold without counting.

    // ---- bracket search: interpolated + midpoint probe pair per pass ----
    // Invariant: c_lo = #{key>=lo} >= K_SEL > c_hi = #{key>=hi}; strict
    // shrink each pass (midpoint safeguards) -> terminates.
    while (c_lo != K_SEL && (hi - lo) > 1u) {
        const unsigned int span = hi - lo;
        unsigned int o1 = (unsigned int)((float)(c_lo - K_SEL) * (float)span /
                                         (float)(c_lo - c_hi));
        unsigned int o2 = span >> 1;
        if (o1 < 1u) o1 = 1u;
        if (o1 > span - 1u) o1 = span - 1u;
        const unsigned int mA = lo + (o1 < o2 ? o1 : o2);
        const unsigned int mB = lo + (o1 < o2 ? o2 : o1);   // mA <= mB, both in (lo,hi)

        const unsigned int s = count_ge2(key, mA, mB);
        const unsigned int cA = s & 0xFFFFu;
        const unsigned int cB = s >> 16;

        if (cB >= K_SEL)      { lo = mB; c_lo = cB; }
        else if (cA >= K_SEL) { lo = mA; c_lo = cA; hi = mB; c_hi = cB; }
        else                  { hi = mA; c_hi = cA; }
    }

    // ---- end state ----
    unsigned int SEL_B, kkf, tieK;
    if (c_lo == K_SEL) { SEL_B = lo; kkf = 0u;           tieK = 0u; } // unique top-K set
    else               { SEL_B = hi; kkf = K_SEL - c_hi; tieK = lo; } // hi==lo+1, T==lo

    unsigned int sel = 0u, alive = 0u;
    #pragma unroll
    for (int j = 0; j < SLOTS; ++j) {
        sel   |= (key[j] >= SEL_B) ? (1u << j) : 0u;
        alive |= (key[j] == tieK)  ? (1u << j) : 0u;
    }

    // ---- ranks: exclusive prefix over lanes of packed (gt<<16 | eq) ----
    const unsigned int mine =
        ((unsigned int)__popc(sel) << 16) | (unsigned int)__popc(alive);
    unsigned int run = wave_incl_scan(mine) - mine;  // exclusive prefix (packed)

    unsigned short* wb = ws_idx + ((size_t)bb * n_samples + ss) * K_SEL;
    float* orow = out + (size_t)bb * (K_SEL * D_DIM);
    const int base_i = lane * SLOTS;
    unsigned int both = sel | alive;
    while (both) {
        const int j = __builtin_ctz(both);
        both &= both - 1u;
        const unsigned int gtp = run >> 16;
        const unsigned int eqp = run & 0xFFFFu;
        if (sel & (1u << j)) {
            const unsigned int rank = gtp + (eqp < kkf ? eqp : kkf);
            if (USE_WS) wb[rank] = (unsigned short)(base_i + j);
            else atomicAdd(orow + (size_t)rank * D_DIM + (base_i + j), inv_n);
            run += 0x10000u;
        } else {
            if (eqp < kkf) {
                if (USE_WS) wb[gtp + eqp] = (unsigned short)(base_i + j);
                else atomicAdd(orow + (size_t)(gtp + eqp) * D_DIM + (base_i + j), inv_n);
            }
            run += 1u;
        }
    }
}

// ---------------- Phase B: histogram + coalesced write ----------------
__global__ __launch_bounds__(256)
void ptopk_hist(const unsigned short* __restrict__ ws_idx,  // [b][n_samples][K_SEL]
                float* __restrict__ out,                    // [b*K_SEL][D_DIM]
                int n_samples, float inv_n) {
    __shared__ unsigned int cnt[D_DIM];
    const int tid = threadIdx.x;
    #pragma unroll
    for (int c = 0; c < D_DIM / 256; ++c) cnt[c * 256 + tid] = 0u;
    __syncthreads();

    const int b_ = blockIdx.x / K_SEL;
    const int r_ = blockIdx.x - b_ * K_SEL;
    const unsigned short* src = ws_idx + (size_t)b_ * n_samples * K_SEL + r_;
    for (int s = tid; s < n_samples; s += 256)
        atomicAdd(&cnt[src[(size_t)s * K_SEL]], 1u);
    __syncthreads();

    float4* dst = reinterpret_cast<float4*>(out + (size_t)blockIdx.x * D_DIM);
    const int i = tid * 4;
    dst[tid] = make_float4(cnt[i] * inv_n, cnt[i + 1] * inv_n,
                           cnt[i + 2] * inv_n, cnt[i + 3] * inv_n);
}

__global__ __launch_bounds__(256)
void zero_kernel(float4* __restrict__ p, int n4) {
    const int i = blockIdx.x * 256 + threadIdx.x;
    if (i < n4) p[i] = make_float4(0.f, 0.f, 0.f, 0.f);
}

extern "C" void kernel_launch(void* const* d_in, const int* in_sizes, int n_in,
                              void* d_out, int out_size, void* d_ws, size_t ws_size,
                              hipStream_t stream) {
    const float* x     = (const float*)d_in[0];
    const float* noise = (const float*)d_in[1];
    float* out = (float*)d_out;

    const int d = D_DIM;                       // 1024
    const int b = in_sizes[0] / d;             // 32
    const int n = in_sizes[1] / in_sizes[0];   // 250
    const int rows = b * n;                    // 8000
    const float inv_n = 1.0f / (float)n;
    const int grid = (rows + WAVES_PER_BLOCK - 1) / WAVES_PER_BLOCK;

    const size_t ws_needed = (size_t)b * K_SEL * n * sizeof(unsigned short);
    if (ws_size >= ws_needed) {
        // two-phase, atomic-free path
        unsigned short* ws_idx = (unsigned short*)d_ws;
        ptopk_select<true><<<grid, BLOCK, 0, stream>>>(x, noise, ws_idx, out,
                                                       n, inv_n, rows);
        ptopk_hist<<<b * K_SEL, 256, 0, stream>>>(ws_idx, out, n, inv_n);
    } else {
        // fallback: atomic-scatter path
        const int n4 = out_size / 4;
        zero_kernel<<<(n4 + 255) / 256, 256, 0, stream>>>((float4*)out, n4);
        ptopk_select<false><<<grid, BLOCK, 0, stream>>>(x, noise, nullptr, out,
                                                        n, inv_n, rows);
    }
}

// Round 9
// 26.262 us; speedup vs baseline: 3.9080x; 1.0234x over previous
//
#include <hip/hip_runtime.h>

// PerturbedTopK: per (b,n) row of d=1024, top-k (k=102) indices of
// x[b] + sigma*noise[b,n], sorted ascending; out[b, rank, idx] += 1/n.
//
// R9: two-phase.
//  Phase A (select): one wave per row. 6-bound packed statistical grid,
//    interpolated+midpoint probe pairs (packed 16-bit counts, DPP trees),
//    exact bracket invariant c(lo)>=K>c(hi). Stores selected u16 index
//    at ws[b][sample][rank] with record stride K_PAD=104 (208B, 16-aligned).
//  Phase B (hist): one block per (b, 4-rank group): each thread loads ONE
//    aligned u64 = 4 ranks of one sample (4x fewer line-fetches than
//    per-rank blocks), LDS hist[4][1024], coalesced float4 row writes.

#define D_DIM 1024
#define K_SEL 102
#define K_PAD 104   // ws record stride in u16; multiple of 8 -> aligned u64 groups
#define RPB 4       // ranks per hist block
#define SIGMA 0.05f
#define WAVES_PER_BLOCK 4
#define BLOCK (WAVES_PER_BLOCK * 64)
#define SLOTS 16    // D_DIM / 64 elements per lane

__device__ __forceinline__ unsigned int float_to_key(float f) {
    unsigned int u = __float_as_uint(f);
    return (u & 0x80000000u) ? ~u : (u | 0x80000000u);  // larger float -> larger uint
}

// wave64 inclusive scan (DPP row_shr tree + masked row broadcasts).
__device__ __forceinline__ unsigned int wave_incl_scan(unsigned int v) {
    v += (unsigned int)__builtin_amdgcn_update_dpp(0, (int)v, 0x111, 0xF, 0xF, false); // row_shr:1
    v += (unsigned int)__builtin_amdgcn_update_dpp(0, (int)v, 0x112, 0xF, 0xF, false); // row_shr:2
    v += (unsigned int)__builtin_amdgcn_update_dpp(0, (int)v, 0x114, 0xF, 0xF, false); // row_shr:4
    v += (unsigned int)__builtin_amdgcn_update_dpp(0, (int)v, 0x118, 0xF, 0xF, false); // row_shr:8
    v += (unsigned int)__builtin_amdgcn_update_dpp(0, (int)v, 0x142, 0xA, 0xF, false); // row_bcast:15
    v += (unsigned int)__builtin_amdgcn_update_dpp(0, (int)v, 0x143, 0xC, 0xF, false); // row_bcast:31
    return v;
}
__device__ __forceinline__ unsigned int wave_sum_u32(unsigned int v) {
    return (unsigned int)__builtin_amdgcn_readlane((int)wave_incl_scan(v), 63);
}

// packed counts of {key >= m1} and {key >= m2}<<16 across the wave's 1024 elems
__device__ __forceinline__ unsigned int count_ge2(const unsigned int* key,
                                                  unsigned int m1, unsigned int m2) {
    unsigned int a = 0, b = 0;
    #pragma unroll
    for (int j = 0; j < SLOTS; ++j) {
        a += (key[j] >= m1) ? 1u : 0u;
        b += (key[j] >= m2) ? 1u : 0u;
    }
    return wave_sum_u32(a | (b << 16));
}

// ---------------- Phase A: select + index store ----------------
template <bool USE_WS>
__global__ __launch_bounds__(BLOCK)
void ptopk_select(const float* __restrict__ x,
                  const float* __restrict__ noise,
                  unsigned short* __restrict__ ws_idx,  // [b][n_samples][K_PAD]
                  float* __restrict__ out,              // fallback path only
                  int n_samples, float inv_n, int nrows) {
    const int wid  = threadIdx.x >> 6;
    const int lane = threadIdx.x & 63;
    const int row  = blockIdx.x * WAVES_PER_BLOCK + wid;
    if (row >= nrows) return;                    // wave-uniform
    const int bb = row / n_samples;
    const int ss = row - bb * n_samples;

    const float4* nrow =
        reinterpret_cast<const float4*>(noise + (size_t)row * D_DIM + lane * SLOTS);
    const float4* xrow =
        reinterpret_cast<const float4*>(x + (size_t)bb * D_DIM + lane * SLOTS);

    unsigned int key[SLOTS];
    #pragma unroll
    for (int c = 0; c < 4; ++c) {
        const float4 nv = nrow[c];
        const float4 xv = xrow[c];
        key[c*4+0] = float_to_key(fmaf(nv.x, SIGMA, xv.x));
        key[c*4+1] = float_to_key(fmaf(nv.y, SIGMA, xv.y));
        key[c*4+2] = float_to_key(fmaf(nv.z, SIGMA, xv.z));
        key[c*4+3] = float_to_key(fmaf(nv.w, SIGMA, xv.w));
    }

    // ---- initial 6-bound grid (one pass, three packed DPP reductions) ----
    // threshold order-stat ~ N(1.284, 0.053); grid covers ~±4 sigma.
    // Outlier rows fall into the generic outer brackets (exact, just slower).
    const unsigned int B1 = float_to_key(1.07f);
    const unsigned int B2 = float_to_key(1.17f);
    const unsigned int B3 = float_to_key(1.25f);
    const unsigned int B4 = float_to_key(1.32f);
    const unsigned int B5 = float_to_key(1.40f);
    const unsigned int B6 = float_to_key(1.50f);
    unsigned int pA = 0, pB = 0, pC = 0;
    #pragma unroll
    for (int j = 0; j < SLOTS; ++j) {
        pA += ((key[j] >= B1) ? 1u : 0u) + ((key[j] >= B2) ? 0x10000u : 0u);
        pB += ((key[j] >= B3) ? 1u : 0u) + ((key[j] >= B4) ? 0x10000u : 0u);
        pC += ((key[j] >= B5) ? 1u : 0u) + ((key[j] >= B6) ? 0x10000u : 0u);
    }
    const unsigned int tA = wave_sum_u32(pA);
    const unsigned int tB = wave_sum_u32(pB);
    const unsigned int tC = wave_sum_u32(pC);
    const unsigned int c1 = tA & 0xFFFFu, c2 = tA >> 16;
    const unsigned int c3 = tB & 0xFFFFu, c4 = tB >> 16;
    const unsigned int c5 = tC & 0xFFFFu, c6 = tC >> 16;

    unsigned int lo, hi, c_lo, c_hi;
    if (c6 >= K_SEL)      { lo = B6; c_lo = c6;    hi = 0xFFFFFFFFu; c_hi = 0u; }
    else if (c5 >= K_SEL) { lo = B5; c_lo = c5;    hi = B6; c_hi = c6; }
    else if (c4 >= K_SEL) { lo = B4; c_lo = c4;    hi = B5; c_hi = c5; }
    else if (c3 >= K_SEL) { lo = B3; c_lo = c3;    hi = B4; c_hi = c4; }
    else if (c2 >= K_SEL) { lo = B2; c_lo = c2;    hi = B3; c_hi = c3; }
    else if (c1 >= K_SEL) { lo = B1; c_lo = c1;    hi = B2; c_hi = c2; }
    else                  { lo = 0u; c_lo = D_DIM; hi = B1; c_hi = c1; }
    // key==0 (-NaN) and key==0xFFFFFFFF (+NaN) are unreachable from finite
    // inputs, so c(0)=D_DIM and c(MAX)=0 hold without counting.

    // ---- bracket search: interpolated + midpoint probe pair per pass ----
    // Invariant: c_lo = #{key>=lo} >= K_SEL > c_hi = #{key>=hi}; strict
    // shrink each pass (midpoint safeguards) -> terminates.
    while (c_lo != K_SEL && (hi - lo) > 1u) {
        const unsigned int span = hi - lo;
        unsigned int o1 = (unsigned int)((float)(c_lo - K_SEL) * (float)span /
                                         (float)(c_lo - c_hi));
        unsigned int o2 = span >> 1;
        if (o1 < 1u) o1 = 1u;
        if (o1 > span - 1u) o1 = span - 1u;
        const unsigned int mA = lo + (o1 < o2 ? o1 : o2);
        const unsigned int mB = lo + (o1 < o2 ? o2 : o1);   // mA <= mB, both in (lo,hi)

        const unsigned int s = count_ge2(key, mA, mB);
        const unsigned int cA = s & 0xFFFFu;
        const unsigned int cB = s >> 16;

        if (cB >= K_SEL)      { lo = mB; c_lo = cB; }
        else if (cA >= K_SEL) { lo = mA; c_lo = cA; hi = mB; c_hi = cB; }
        else                  { hi = mA; c_hi = cA; }
    }

    // ---- end state ----
    unsigned int SEL_B, kkf, tieK;
    if (c_lo == K_SEL) { SEL_B = lo; kkf = 0u;           tieK = 0u; } // unique top-K set
    else               { SEL_B = hi; kkf = K_SEL - c_hi; tieK = lo; } // hi==lo+1, T==lo

    unsigned int sel = 0u, alive = 0u;
    #pragma unroll
    for (int j = 0; j < SLOTS; ++j) {
        sel   |= (key[j] >= SEL_B) ? (1u << j) : 0u;
        alive |= (key[j] == tieK)  ? (1u << j) : 0u;
    }

    // ---- ranks: exclusive prefix over lanes of packed (gt<<16 | eq) ----
    const unsigned int mine =
        ((unsigned int)__popc(sel) << 16) | (unsigned int)__popc(alive);
    unsigned int run = wave_incl_scan(mine) - mine;  // exclusive prefix (packed)

    unsigned short* wb = ws_idx + ((size_t)bb * n_samples + ss) * K_PAD;
    float* orow = out + (size_t)bb * (K_SEL * D_DIM);
    const int base_i = lane * SLOTS;
    unsigned int both = sel | alive;
    while (both) {
        const int j = __builtin_ctz(both);
        both &= both - 1u;
        const unsigned int gtp = run >> 16;
        const unsigned int eqp = run & 0xFFFFu;
        if (sel & (1u << j)) {
            const unsigned int rank = gtp + (eqp < kkf ? eqp : kkf);
            if (USE_WS) wb[rank] = (unsigned short)(base_i + j);
            else atomicAdd(orow + (size_t)rank * D_DIM + (base_i + j), inv_n);
            run += 0x10000u;
        } else {
            if (eqp < kkf) {
                if (USE_WS) wb[gtp + eqp] = (unsigned short)(base_i + j);
                else atomicAdd(orow + (size_t)(gtp + eqp) * D_DIM + (base_i + j), inv_n);
            }
            run += 1u;
        }
    }
}

// ---------------- Phase B: 4-rank histogram + coalesced write ----------------
__global__ __launch_bounds__(256)
void ptopk_hist(const unsigned short* __restrict__ ws_idx,  // [b][n_samples][K_PAD]
                float* __restrict__ out,                    // [b][K_SEL][D_DIM]
                int n_samples, float inv_n) {
    __shared__ unsigned int cnt[RPB][D_DIM];   // 16 KB
    const int tid  = threadIdx.x;
    const int ngrp = K_PAD / RPB;              // 26
    const int b_   = blockIdx.x / ngrp;
    const int g_   = blockIdx.x - b_ * ngrp;
    const int r0   = g_ * RPB;

    uint4* cz = reinterpret_cast<uint4*>(&cnt[0][0]);
    #pragma unroll
    for (int c = 0; c < (RPB * D_DIM) / (4 * 256); ++c)
        cz[c * 256 + tid] = make_uint4(0u, 0u, 0u, 0u);
    __syncthreads();

    // one aligned u64 per sample = this block's 4 ranks of that sample.
    // byte offset = 208*rec + 8*g_  -> 8-aligned (208 = 16*13).
    for (int s = tid; s < n_samples; s += 256) {
        const unsigned long long v = *reinterpret_cast<const unsigned long long*>(
            ws_idx + ((size_t)b_ * n_samples + s) * K_PAD + r0);
        #pragma unroll
        for (int e = 0; e < RPB; ++e) {
            // pad ranks (>=K_SEL) carry poison garbage: clamp into range; their
            // counts land in hist rows that are never written out.
            const unsigned int idx = (unsigned int)((v >> (16 * e)) & 0xFFFFu) & (D_DIM - 1u);
            atomicAdd(&cnt[e][idx], 1u);
        }
    }
    __syncthreads();

    const int i = tid * 4;
    #pragma unroll
    for (int e = 0; e < RPB; ++e) {
        const int rank = r0 + e;
        if (rank < K_SEL) {
            float4* dst = reinterpret_cast<float4*>(out + ((size_t)b_ * K_SEL + rank) * D_DIM);
            dst[tid] = make_float4(cnt[e][i] * inv_n, cnt[e][i + 1] * inv_n,
                                   cnt[e][i + 2] * inv_n, cnt[e][i + 3] * inv_n);
        }
    }
}

__global__ __launch_bounds__(256)
void zero_kernel(float4* __restrict__ p, int n4) {
    const int i = blockIdx.x * 256 + threadIdx.x;
    if (i < n4) p[i] = make_float4(0.f, 0.f, 0.f, 0.f);
}

extern "C" void kernel_launch(void* const* d_in, const int* in_sizes, int n_in,
                              void* d_out, int out_size, void* d_ws, size_t ws_size,
                              hipStream_t stream) {
    const float* x     = (const float*)d_in[0];
    const float* noise = (const float*)d_in[1];
    float* out = (float*)d_out;

    const int d = D_DIM;                       // 1024
    const int b = in_sizes[0] / d;             // 32
    const int n = in_sizes[1] / in_sizes[0];   // 250
    const int rows = b * n;                    // 8000
    const float inv_n = 1.0f / (float)n;
    const int grid = (rows + WAVES_PER_BLOCK - 1) / WAVES_PER_BLOCK;

    const size_t ws_needed = (size_t)b * n * K_PAD * sizeof(unsigned short);
    if (ws_size >= ws_needed) {
        // two-phase, atomic-free path
        unsigned short* ws_idx = (unsigned short*)d_ws;
        ptopk_select<true><<<grid, BLOCK, 0, stream>>>(x, noise, ws_idx, out,
                                                       n, inv_n, rows);
        ptopk_hist<<<b * (K_PAD / RPB), 256, 0, stream>>>(ws_idx, out, n, inv_n);
    } else {
        // fallback: atomic-scatter path
        const int n4 = out_size / 4;
        zero_kernel<<<(n4 + 255) / 256, 256, 0, stream>>>((float4*)out, n4);
        ptopk_select<false><<<grid, BLOCK, 0, stream>>>(x, noise, nullptr, out,
                                                        n, inv_n, rows);
    }
}